// Round 1
// baseline (556.981 us; speedup 1.0000x reference)
//
#include <hip/hip_runtime.h>

#define S_LEN 512
#define D_DIM 512
#define BATCH 32
#define M_ROWS (BATCH * S_LEN)   // 16384
#define NLAYER 3

typedef unsigned short ushort_t;
typedef __bf16 bf16_t;
typedef bf16_t bf16x8 __attribute__((ext_vector_type(8)));
typedef unsigned short u16x8 __attribute__((ext_vector_type(8)));
typedef float f32x4 __attribute__((ext_vector_type(4)));

typedef const __attribute__((address_space(1))) unsigned int* gptr_t;
typedef __attribute__((address_space(3))) unsigned int* lptr_t;

__device__ __forceinline__ ushort_t f2bf(float f) {
  unsigned u = __float_as_uint(f);
  unsigned r = (u + 0x7fffu + ((u >> 16) & 1u)) >> 16;   // RNE
  return (ushort_t)r;
}

// ---------------------------------------------------------------------------
// Weight prep: w[k][n] fp32 -> wt[n][k] bf16 (B^T layout for the GEMM)
// grid (16,16,12), block (32,8). z: l = z/4, m = z%4 in {fw1,fw2,bw1,bw2}
// ---------------------------------------------------------------------------
__global__ __launch_bounds__(256)
void wprep_kernel(const float* __restrict__ fw1, const float* __restrict__ fw2,
                  const float* __restrict__ bw1, const float* __restrict__ bw2,
                  ushort_t* __restrict__ wt1, ushort_t* __restrict__ wt2) {
  int z = blockIdx.z;
  int l = z >> 2, m = z & 3;
  const float* bases[4] = {fw1, fw2, bw1, bw2};
  const float* src = bases[m] + (size_t)l * D_DIM * D_DIM;
  int streamIdx = m >> 1;    // 0 fwd, 1 bwd
  int which = m & 1;         // 0 -> w1, 1 -> w2
  ushort_t* dst = (which ? wt2 : wt1) + ((size_t)streamIdx * NLAYER + l) * D_DIM * D_DIM;

  __shared__ float tile[32][33];
  int n0 = blockIdx.x * 32, k0 = blockIdx.y * 32;
  int tx = threadIdx.x, ty = threadIdx.y;
#pragma unroll
  for (int i = 0; i < 32; i += 8)
    tile[ty + i][tx] = src[(size_t)(k0 + ty + i) * D_DIM + n0 + tx];
  __syncthreads();
#pragma unroll
  for (int i = 0; i < 32; i += 8)
    dst[(size_t)(n0 + ty + i) * D_DIM + k0 + tx] = f2bf(tile[tx][ty + i]);
}

// ---------------------------------------------------------------------------
// Fused window-conv + LayerNorm. grid (M_ROWS/4, 2), block 256 (1 wave/row).
// Writes yf fp32 [2][M][512] (residual) and yln bf16 [2][M][512] (GEMM1 A).
// ---------------------------------------------------------------------------
__global__ __launch_bounds__(256)
void conv_ln_kernel(const float* __restrict__ srcF, int strideF,
                    const float* __restrict__ srcB, int strideB,
                    const float* __restrict__ padLo, const float* __restrict__ padHi,
                    const float* __restrict__ wF, const float* __restrict__ wB,
                    const float* __restrict__ gF, const float* __restrict__ beF,
                    const float* __restrict__ gB, const float* __restrict__ beB,
                    float* __restrict__ yf, ushort_t* __restrict__ yln) {
  int z = blockIdx.y;
  int tid = threadIdx.x;
  int lane = tid & 63;
  int rl = tid >> 6;
  int row = blockIdx.x * 4 + rl;        // 0..16383
  int t = row & (S_LEN - 1);
  const float* src = z ? srcB : srcF;
  int stride = z ? strideB : strideF;
  const float* wv = z ? wB : wF;
  const float* gv = z ? gB : gF;
  const float* bv = z ? beB : beF;
  int toff = z ? 0 : -3;                // fwd window [t-3,t], bwd [t,t+3]
  int c0 = lane * 4, c1 = 256 + lane * 4;

  float4 a0 = make_float4(0.f, 0.f, 0.f, 0.f);
  float4 a1 = make_float4(0.f, 0.f, 0.f, 0.f);
#pragma unroll
  for (int k = 0; k < 4; ++k) {
    int tt = t + k + toff;
    const float* rp;
    if (tt < 0)            rp = padLo + (size_t)(tt + 3) * D_DIM;      // fwd_pad[l]
    else if (tt >= S_LEN)  rp = padHi + (size_t)(tt - S_LEN) * D_DIM;  // bwd_pad[l]
    else                   rp = src + (size_t)(row + k + toff) * stride;
    float wk = wv[k];
    float4 u0 = *(const float4*)(rp + c0);
    float4 u1 = *(const float4*)(rp + c1);
    a0.x = fmaf(wk, u0.x, a0.x); a0.y = fmaf(wk, u0.y, a0.y);
    a0.z = fmaf(wk, u0.z, a0.z); a0.w = fmaf(wk, u0.w, a0.w);
    a1.x = fmaf(wk, u1.x, a1.x); a1.y = fmaf(wk, u1.y, a1.y);
    a1.z = fmaf(wk, u1.z, a1.z); a1.w = fmaf(wk, u1.w, a1.w);
  }
  // mean
  float s = a0.x + a0.y + a0.z + a0.w + a1.x + a1.y + a1.z + a1.w;
#pragma unroll
  for (int o = 32; o; o >>= 1) s += __shfl_xor(s, o);
  float mean = s * (1.0f / 512.0f);
  // unbiased variance (ddof=1)
  float q = 0.f, dx;
  dx = a0.x - mean; q = fmaf(dx, dx, q);
  dx = a0.y - mean; q = fmaf(dx, dx, q);
  dx = a0.z - mean; q = fmaf(dx, dx, q);
  dx = a0.w - mean; q = fmaf(dx, dx, q);
  dx = a1.x - mean; q = fmaf(dx, dx, q);
  dx = a1.y - mean; q = fmaf(dx, dx, q);
  dx = a1.z - mean; q = fmaf(dx, dx, q);
  dx = a1.w - mean; q = fmaf(dx, dx, q);
#pragma unroll
  for (int o = 32; o; o >>= 1) q += __shfl_xor(q, o);
  float sd = sqrtf(q * (1.0f / 511.0f));
  float inv = 1.0f / (sd + 1e-6f);

  size_t base = ((size_t)z * M_ROWS + row) * D_DIM;
  *(float4*)(yf + base + c0) = a0;
  *(float4*)(yf + base + c1) = a1;

  float4 g0 = *(const float4*)(gv + c0), g1 = *(const float4*)(gv + c1);
  float4 b0 = *(const float4*)(bv + c0), b1 = *(const float4*)(bv + c1);
  ushort_t p0[4], p1[4];
  p0[0] = f2bf(g0.x * ((a0.x - mean) * inv) + b0.x);
  p0[1] = f2bf(g0.y * ((a0.y - mean) * inv) + b0.y);
  p0[2] = f2bf(g0.z * ((a0.z - mean) * inv) + b0.z);
  p0[3] = f2bf(g0.w * ((a0.w - mean) * inv) + b0.w);
  p1[0] = f2bf(g1.x * ((a1.x - mean) * inv) + b1.x);
  p1[1] = f2bf(g1.y * ((a1.y - mean) * inv) + b1.y);
  p1[2] = f2bf(g1.z * ((a1.z - mean) * inv) + b1.z);
  p1[3] = f2bf(g1.w * ((a1.w - mean) * inv) + b1.w);
  *(uint2*)(yln + base + c0) = *(uint2*)p0;
  *(uint2*)(yln + base + c1) = *(uint2*)p1;
}

// ---------------------------------------------------------------------------
// bf16 MFMA GEMM, 128x128 tile, BK=32, 4 waves (2x2 of 64x64), m97 structure.
// A [2][M][512] bf16 (z-indexed); Bt per-stream [512][512] bf16 (N-major).
// EPI 1: H = relu(C + b1) -> bf16.  EPI 2: out = C + b2 + yf -> fp32 (stride 1024).
// ---------------------------------------------------------------------------
template <int EPI>
__global__ __launch_bounds__(256)
void gemm_kernel(const ushort_t* __restrict__ A,
                 const ushort_t* __restrict__ Bt_f, const ushort_t* __restrict__ Bt_b,
                 const float* __restrict__ bias_f, const float* __restrict__ bias_b,
                 const float* __restrict__ resid,   // yf base (EPI==2)
                 ushort_t* __restrict__ Hout,       // (EPI==1)
                 float* __restrict__ Cout) {        // d_out + l*M*1024 (EPI==2)
  const int K = 512;
  int mblk = blockIdx.x;   // 0..127
  int nblk = blockIdx.y;   // 0..3
  int z = blockIdx.z;      // stream
  const ushort_t* Ab = A + (size_t)z * M_ROWS * K + (size_t)mblk * 128 * K;
  const ushort_t* Bb = (z ? Bt_b : Bt_f) + (size_t)nblk * 128 * K;

  __shared__ __attribute__((aligned(16))) ushort_t As[128 * 32];
  __shared__ __attribute__((aligned(16))) ushort_t Bs[128 * 32];

  int tid = threadIdx.x, lane = tid & 63, wave = tid >> 6;
  int wr = wave >> 1, wc = wave & 1;
  int lm = lane & 15, lq = lane >> 4;

  f32x4 acc[4][4] = {};

  for (int kb = 0; kb < 16; ++kb) {
    int k0 = kb * 32;
#pragma unroll
    for (int i = 0; i < 2; ++i) {
      int slot = i * 256 + tid;
      int row = slot >> 2, kc = slot & 3;
      const ushort_t* ga = Ab + (size_t)row * K + k0 + kc * 8;
      const ushort_t* gb = Bb + (size_t)row * K + k0 + kc * 8;
      __builtin_amdgcn_global_load_lds((gptr_t)(const void*)ga,
                                       (lptr_t)(void*)(As + slot * 8), 16, 0, 0);
      __builtin_amdgcn_global_load_lds((gptr_t)(const void*)gb,
                                       (lptr_t)(void*)(Bs + slot * 8), 16, 0, 0);
    }
    __syncthreads();
    bf16x8 a[4], b[4];
#pragma unroll
    for (int i = 0; i < 4; ++i) {
      union { u16x8 u; bf16x8 b; } ua, ub;
      ua.u = *(const u16x8*)&As[(wr * 64 + i * 16 + lm) * 32 + lq * 8];
      ub.u = *(const u16x8*)&Bs[(wc * 64 + i * 16 + lm) * 32 + lq * 8];
      a[i] = ua.b; b[i] = ub.b;
    }
#pragma unroll
    for (int i = 0; i < 4; ++i)
#pragma unroll
      for (int j = 0; j < 4; ++j)
        acc[i][j] = __builtin_amdgcn_mfma_f32_16x16x32_bf16(a[i], b[j], acc[i][j], 0, 0, 0);
    __syncthreads();
  }

  // Epilogue. C/D layout: col = lane&15, row = (lane>>4)*4 + reg  [verified m89/m91]
  const float* bias = z ? bias_b : bias_f;
  if (EPI == 1) {
    ushort_t* Hb = Hout + (size_t)z * M_ROWS * 512;
#pragma unroll
    for (int i = 0; i < 4; ++i) {
      int mbase = mblk * 128 + wr * 64 + i * 16 + lq * 4;
#pragma unroll
      for (int j = 0; j < 4; ++j) {
        int n = nblk * 128 + wc * 64 + j * 16 + lm;
        float bvn = bias[n];
#pragma unroll
        for (int r = 0; r < 4; ++r) {
          float v = fmaxf(acc[i][j][r] + bvn, 0.0f);
          Hb[(size_t)(mbase + r) * 512 + n] = f2bf(v);
        }
      }
    }
  } else {
    const float* rs = resid + (size_t)z * M_ROWS * 512;
    float* Cb = Cout + (size_t)z * 512;
#pragma unroll
    for (int i = 0; i < 4; ++i) {
      int mbase = mblk * 128 + wr * 64 + i * 16 + lq * 4;
#pragma unroll
      for (int j = 0; j < 4; ++j) {
        int n = nblk * 128 + wc * 64 + j * 16 + lm;
        float bvn = bias[n];
#pragma unroll
        for (int r = 0; r < 4; ++r) {
          float v = acc[i][j][r] + bvn + rs[(size_t)(mbase + r) * 512 + n];
          Cb[(size_t)(mbase + r) * 1024 + n] = v;
        }
      }
    }
  }
}

// ---------------------------------------------------------------------------
extern "C" void kernel_launch(void* const* d_in, const int* in_sizes, int n_in,
                              void* d_out, int out_size, void* d_ws, size_t ws_size,
                              hipStream_t stream) {
  const float* x        = (const float*)d_in[0];
  const float* fwd_pad  = (const float*)d_in[1];
  const float* bwd_pad  = (const float*)d_in[2];
  const float* fwd_w    = (const float*)d_in[3];
  const float* bwd_w    = (const float*)d_in[4];
  const float* fwd_w1   = (const float*)d_in[5];
  const float* fwd_b1   = (const float*)d_in[6];
  const float* fwd_w2   = (const float*)d_in[7];
  const float* fwd_b2   = (const float*)d_in[8];
  const float* fwd_g    = (const float*)d_in[9];
  const float* fwd_beta = (const float*)d_in[10];
  const float* bwd_w1   = (const float*)d_in[11];
  const float* bwd_b1   = (const float*)d_in[12];
  const float* bwd_w2   = (const float*)d_in[13];
  const float* bwd_b2   = (const float*)d_in[14];
  const float* bwd_g    = (const float*)d_in[15];
  const float* bwd_beta = (const float*)d_in[16];
  float* out = (float*)d_out;

  // workspace layout
  const size_t WSZ = (size_t)D_DIM * D_DIM;           // 262144
  ushort_t* wt1 = (ushort_t*)d_ws;                    // [2][3][512][512] bf16
  ushort_t* wt2 = wt1 + 2 * NLAYER * WSZ;             // same
  float* yf = (float*)(wt2 + 2 * NLAYER * WSZ);       // [2][M][512] fp32
  ushort_t* yln = (ushort_t*)(yf + (size_t)2 * M_ROWS * D_DIM);
  ushort_t* h = yln + (size_t)2 * M_ROWS * D_DIM;

  wprep_kernel<<<dim3(16, 16, 12), dim3(32, 8), 0, stream>>>(
      fwd_w1, fwd_w2, bwd_w1, bwd_w2, wt1, wt2);

  for (int l = 0; l < NLAYER; ++l) {
    const float *srcF, *srcB;
    int strF, strB;
    if (l == 0) {
      srcF = x; srcB = x; strF = 512; strB = 512;
    } else {
      srcF = out + (size_t)(l - 1) * M_ROWS * 1024;
      srcB = srcF + 512;
      strF = 1024; strB = 1024;
    }
    conv_ln_kernel<<<dim3(M_ROWS / 4, 2), 256, 0, stream>>>(
        srcF, strF, srcB, strB,
        fwd_pad + (size_t)l * 3 * D_DIM, bwd_pad + (size_t)l * 3 * D_DIM,
        fwd_w + l * 4, bwd_w + l * 4,
        fwd_g + l * D_DIM, fwd_beta + l * D_DIM,
        bwd_g + l * D_DIM, bwd_beta + l * D_DIM,
        yf, yln);

    gemm_kernel<1><<<dim3(128, 4, 2), 256, 0, stream>>>(
        yln, wt1 + (size_t)l * WSZ, wt1 + (size_t)(NLAYER + l) * WSZ,
        fwd_b1 + l * D_DIM, bwd_b1 + l * D_DIM,
        nullptr, h, nullptr);

    gemm_kernel<2><<<dim3(128, 4, 2), 256, 0, stream>>>(
        h, wt2 + (size_t)l * WSZ, wt2 + (size_t)(NLAYER + l) * WSZ,
        fwd_b2 + l * D_DIM, bwd_b2 + l * D_DIM,
        yf, nullptr, out + (size_t)l * M_ROWS * 1024);
  }
}

// Round 2
// 513.402 us; speedup vs baseline: 1.0849x; 1.0849x over previous
//
#include <hip/hip_runtime.h>

#define S_LEN 512
#define D_DIM 512
#define BATCH 32
#define M_ROWS (BATCH * S_LEN)   // 16384
#define NLAYER 3

typedef unsigned short ushort_t;
typedef __bf16 bf16_t;
typedef bf16_t bf16x8 __attribute__((ext_vector_type(8)));
typedef unsigned short u16x8 __attribute__((ext_vector_type(8)));
typedef float f32x4 __attribute__((ext_vector_type(4)));

typedef const __attribute__((address_space(1))) unsigned int* gptr_t;
typedef __attribute__((address_space(3))) unsigned int* lptr_t;

__device__ __forceinline__ ushort_t f2bf(float f) {
  unsigned u = __float_as_uint(f);
  unsigned r = (u + 0x7fffu + ((u >> 16) & 1u)) >> 16;   // RNE
  return (ushort_t)r;
}

// ---------------------------------------------------------------------------
// Weight prep: w[k][n] fp32 -> wt[n][k] bf16 (B^T layout for the GEMM)
// ---------------------------------------------------------------------------
__global__ __launch_bounds__(256)
void wprep_kernel(const float* __restrict__ fw1, const float* __restrict__ fw2,
                  const float* __restrict__ bw1, const float* __restrict__ bw2,
                  ushort_t* __restrict__ wt1, ushort_t* __restrict__ wt2) {
  int z = blockIdx.z;
  int l = z >> 2, m = z & 3;
  const float* bases[4] = {fw1, fw2, bw1, bw2};
  const float* src = bases[m] + (size_t)l * D_DIM * D_DIM;
  int streamIdx = m >> 1;
  int which = m & 1;
  ushort_t* dst = (which ? wt2 : wt1) + ((size_t)streamIdx * NLAYER + l) * D_DIM * D_DIM;

  __shared__ float tile[32][33];
  int n0 = blockIdx.x * 32, k0 = blockIdx.y * 32;
  int tx = threadIdx.x, ty = threadIdx.y;
#pragma unroll
  for (int i = 0; i < 32; i += 8)
    tile[ty + i][tx] = src[(size_t)(k0 + ty + i) * D_DIM + n0 + tx];
  __syncthreads();
#pragma unroll
  for (int i = 0; i < 32; i += 8)
    dst[(size_t)(n0 + ty + i) * D_DIM + k0 + tx] = f2bf(tile[tx][ty + i]);
}

// ---------------------------------------------------------------------------
// Fused window-conv + LayerNorm. grid (M_ROWS/4, 2), block 256 (1 wave/row).
// Writes ONLY yln bf16 [2][M][512] (GEMM1 A). Residual is recomputed in the
// GEMM2 epilogue (fp32 exact) -- no yf buffer.
// ---------------------------------------------------------------------------
__global__ __launch_bounds__(256)
void conv_ln_kernel(const float* __restrict__ srcF, int strideF,
                    const float* __restrict__ srcB, int strideB,
                    const float* __restrict__ padLo, const float* __restrict__ padHi,
                    const float* __restrict__ wF, const float* __restrict__ wB,
                    const float* __restrict__ gF, const float* __restrict__ beF,
                    const float* __restrict__ gB, const float* __restrict__ beB,
                    ushort_t* __restrict__ yln) {
  int z = blockIdx.y;
  int tid = threadIdx.x;
  int lane = tid & 63;
  int rl = tid >> 6;
  int row = blockIdx.x * 4 + rl;
  int t = row & (S_LEN - 1);
  const float* src = z ? srcB : srcF;
  int stride = z ? strideB : strideF;
  const float* wv = z ? wB : wF;
  const float* gv = z ? gB : gF;
  const float* bv = z ? beB : beF;
  int toff = z ? 0 : -3;                // fwd window [t-3,t], bwd [t,t+3]
  int c0 = lane * 4, c1 = 256 + lane * 4;

  float4 a0 = make_float4(0.f, 0.f, 0.f, 0.f);
  float4 a1 = make_float4(0.f, 0.f, 0.f, 0.f);
#pragma unroll
  for (int k = 0; k < 4; ++k) {
    int tt = t + k + toff;
    const float* rp;
    if (tt < 0)            rp = padLo + (size_t)(tt + 3) * D_DIM;
    else if (tt >= S_LEN)  rp = padHi + (size_t)(tt - S_LEN) * D_DIM;
    else                   rp = src + (size_t)(row + k + toff) * stride;
    float wk = wv[k];
    float4 u0 = *(const float4*)(rp + c0);
    float4 u1 = *(const float4*)(rp + c1);
    a0.x = fmaf(wk, u0.x, a0.x); a0.y = fmaf(wk, u0.y, a0.y);
    a0.z = fmaf(wk, u0.z, a0.z); a0.w = fmaf(wk, u0.w, a0.w);
    a1.x = fmaf(wk, u1.x, a1.x); a1.y = fmaf(wk, u1.y, a1.y);
    a1.z = fmaf(wk, u1.z, a1.z); a1.w = fmaf(wk, u1.w, a1.w);
  }
  float s = a0.x + a0.y + a0.z + a0.w + a1.x + a1.y + a1.z + a1.w;
#pragma unroll
  for (int o = 32; o; o >>= 1) s += __shfl_xor(s, o);
  float mean = s * (1.0f / 512.0f);
  float q = 0.f, dx;
  dx = a0.x - mean; q = fmaf(dx, dx, q);
  dx = a0.y - mean; q = fmaf(dx, dx, q);
  dx = a0.z - mean; q = fmaf(dx, dx, q);
  dx = a0.w - mean; q = fmaf(dx, dx, q);
  dx = a1.x - mean; q = fmaf(dx, dx, q);
  dx = a1.y - mean; q = fmaf(dx, dx, q);
  dx = a1.z - mean; q = fmaf(dx, dx, q);
  dx = a1.w - mean; q = fmaf(dx, dx, q);
#pragma unroll
  for (int o = 32; o; o >>= 1) q += __shfl_xor(q, o);
  float sd = sqrtf(q * (1.0f / 511.0f));
  float inv = 1.0f / (sd + 1e-6f);

  size_t base = ((size_t)z * M_ROWS + row) * D_DIM;
  float4 g0 = *(const float4*)(gv + c0), g1 = *(const float4*)(gv + c1);
  float4 b0 = *(const float4*)(bv + c0), b1 = *(const float4*)(bv + c1);
  ushort_t p0[4], p1[4];
  p0[0] = f2bf(g0.x * ((a0.x - mean) * inv) + b0.x);
  p0[1] = f2bf(g0.y * ((a0.y - mean) * inv) + b0.y);
  p0[2] = f2bf(g0.z * ((a0.z - mean) * inv) + b0.z);
  p0[3] = f2bf(g0.w * ((a0.w - mean) * inv) + b0.w);
  p1[0] = f2bf(g1.x * ((a1.x - mean) * inv) + b1.x);
  p1[1] = f2bf(g1.y * ((a1.y - mean) * inv) + b1.y);
  p1[2] = f2bf(g1.z * ((a1.z - mean) * inv) + b1.z);
  p1[3] = f2bf(g1.w * ((a1.w - mean) * inv) + b1.w);
  *(uint2*)(yln + base + c0) = *(uint2*)p0;
  *(uint2*)(yln + base + c1) = *(uint2*)p1;
}

// ---------------------------------------------------------------------------
// bf16 MFMA GEMM, 128x128 tile, BK=32, 4 waves, m97 structure.
// Launched 1-D with 1024 blocks. XCD-aware swizzle: consecutive linear block
// IDs round-robin across 8 XCDs, so the 4 nblk-siblings of one (mblk,z) A-tile
// are spaced 8 apart -> same XCD -> A tile served from that XCD's L2 (read
// from HBM once instead of 4x).
// EPI 1: H = relu(C + b1) -> bf16.
// EPI 2: out = C + b2 + conv(src) -> fp32 (stride 1024); residual recomputed
//        in-register from the layer input (fp32 exact, L1/L2-resident taps).
// ---------------------------------------------------------------------------
template <int EPI>
__global__ __launch_bounds__(256)
void gemm_kernel(const ushort_t* __restrict__ A,
                 const ushort_t* __restrict__ Bt_f, const ushort_t* __restrict__ Bt_b,
                 const float* __restrict__ bias_f, const float* __restrict__ bias_b,
                 ushort_t* __restrict__ Hout,       // (EPI==1)
                 float* __restrict__ Cout,          // d_out + l*M*1024 (EPI==2)
                 const float* __restrict__ srcF, const float* __restrict__ srcB,
                 int srcStride,
                 const float* __restrict__ padLo, const float* __restrict__ padHi,
                 const float* __restrict__ wF, const float* __restrict__ wB) {
  const int K = 512;
  int lin = blockIdx.x;
  int xcd = lin & 7;
  int slot = lin >> 3;
  int nblk = slot & 3;
  int G = xcd * 32 + (slot >> 2);      // 0..255
  int z = G >> 7;                      // stream
  int mblk = G & 127;

  const ushort_t* Ab = A + (size_t)z * M_ROWS * K + (size_t)mblk * 128 * K;
  const ushort_t* Bb = (z ? Bt_b : Bt_f) + (size_t)nblk * 128 * K;

  __shared__ __attribute__((aligned(16))) ushort_t As[128 * 32];
  __shared__ __attribute__((aligned(16))) ushort_t Bs[128 * 32];

  int tid = threadIdx.x, lane = tid & 63, wave = tid >> 6;
  int wr = wave >> 1, wc = wave & 1;
  int lm = lane & 15, lq = lane >> 4;

  f32x4 acc[4][4] = {};

  for (int kb = 0; kb < 16; ++kb) {
    int k0 = kb * 32;
#pragma unroll
    for (int i = 0; i < 2; ++i) {
      int slot2 = i * 256 + tid;
      int row = slot2 >> 2, kc = slot2 & 3;
      const ushort_t* ga = Ab + (size_t)row * K + k0 + kc * 8;
      const ushort_t* gb = Bb + (size_t)row * K + k0 + kc * 8;
      __builtin_amdgcn_global_load_lds((gptr_t)(const void*)ga,
                                       (lptr_t)(void*)(As + slot2 * 8), 16, 0, 0);
      __builtin_amdgcn_global_load_lds((gptr_t)(const void*)gb,
                                       (lptr_t)(void*)(Bs + slot2 * 8), 16, 0, 0);
    }
    __syncthreads();
    bf16x8 a[4], b[4];
#pragma unroll
    for (int i = 0; i < 4; ++i) {
      union { u16x8 u; bf16x8 b; } ua, ub;
      ua.u = *(const u16x8*)&As[(wr * 64 + i * 16 + lm) * 32 + lq * 8];
      ub.u = *(const u16x8*)&Bs[(wc * 64 + i * 16 + lm) * 32 + lq * 8];
      a[i] = ua.b; b[i] = ub.b;
    }
#pragma unroll
    for (int i = 0; i < 4; ++i)
#pragma unroll
      for (int j = 0; j < 4; ++j)
        acc[i][j] = __builtin_amdgcn_mfma_f32_16x16x32_bf16(a[i], b[j], acc[i][j], 0, 0, 0);
    __syncthreads();
  }

  // Epilogue. C/D layout: col = lane&15, row = (lane>>4)*4 + reg  [m89/m91]
  const float* bias = z ? bias_b : bias_f;
  if (EPI == 1) {
    ushort_t* Hb = Hout + (size_t)z * M_ROWS * 512;
#pragma unroll
    for (int i = 0; i < 4; ++i) {
      int mbase = mblk * 128 + wr * 64 + i * 16 + lq * 4;
#pragma unroll
      for (int j = 0; j < 4; ++j) {
        int n = nblk * 128 + wc * 64 + j * 16 + lm;
        float bvn = bias[n];
#pragma unroll
        for (int r = 0; r < 4; ++r) {
          float v = fmaxf(acc[i][j][r] + bvn, 0.0f);
          Hb[(size_t)(mbase + r) * 512 + n] = f2bf(v);
        }
      }
    }
  } else {
    const float* src = z ? srcB : srcF;
    const float* wv = z ? wB : wF;
    int toff = z ? 0 : -3;
    float w0 = wv[0], w1 = wv[1], w2 = wv[2], w3 = wv[3];
    float* Cb = Cout + (size_t)z * 512;
#pragma unroll
    for (int i = 0; i < 4; ++i) {
      int mbase = mblk * 128 + wr * 64 + i * 16 + lq * 4;
      int t0 = mbase & (S_LEN - 1);
      int rb = mbase - t0;                   // batch start row
      const float* rp[7];
#pragma unroll
      for (int q = 0; q < 7; ++q) {
        int tt = t0 + toff + q;
        rp[q] = (tt < 0)       ? padLo + (size_t)(tt + 3) * D_DIM
              : (tt >= S_LEN)  ? padHi + (size_t)(tt - S_LEN) * D_DIM
                               : src + (size_t)(rb + tt) * srcStride;
      }
#pragma unroll
      for (int j = 0; j < 4; ++j) {
        int n = nblk * 128 + wc * 64 + j * 16 + lm;
        float v[7];
#pragma unroll
        for (int q = 0; q < 7; ++q) v[q] = rp[q][n];
        float bvn = bias[n];
#pragma unroll
        for (int r = 0; r < 4; ++r) {
          float y = w0 * v[r] + w1 * v[r + 1] + w2 * v[r + 2] + w3 * v[r + 3];
          Cb[(size_t)(mbase + r) * 1024 + n] = acc[i][j][r] + bvn + y;
        }
      }
    }
  }
}

// ---------------------------------------------------------------------------
extern "C" void kernel_launch(void* const* d_in, const int* in_sizes, int n_in,
                              void* d_out, int out_size, void* d_ws, size_t ws_size,
                              hipStream_t stream) {
  const float* x        = (const float*)d_in[0];
  const float* fwd_pad  = (const float*)d_in[1];
  const float* bwd_pad  = (const float*)d_in[2];
  const float* fwd_w    = (const float*)d_in[3];
  const float* bwd_w    = (const float*)d_in[4];
  const float* fwd_w1   = (const float*)d_in[5];
  const float* fwd_b1   = (const float*)d_in[6];
  const float* fwd_w2   = (const float*)d_in[7];
  const float* fwd_b2   = (const float*)d_in[8];
  const float* fwd_g    = (const float*)d_in[9];
  const float* fwd_beta = (const float*)d_in[10];
  const float* bwd_w1   = (const float*)d_in[11];
  const float* bwd_b1   = (const float*)d_in[12];
  const float* bwd_w2   = (const float*)d_in[13];
  const float* bwd_b2   = (const float*)d_in[14];
  const float* bwd_g    = (const float*)d_in[15];
  const float* bwd_beta = (const float*)d_in[16];
  float* out = (float*)d_out;

  const size_t WSZ = (size_t)D_DIM * D_DIM;           // 262144
  ushort_t* wt1 = (ushort_t*)d_ws;                    // [2][3][512][512] bf16
  ushort_t* wt2 = wt1 + 2 * NLAYER * WSZ;
  ushort_t* yln = wt2 + 2 * NLAYER * WSZ;             // [2][M][512] bf16
  ushort_t* h   = yln + (size_t)2 * M_ROWS * D_DIM;   // [2][M][512] bf16

  wprep_kernel<<<dim3(16, 16, 12), dim3(32, 8), 0, stream>>>(
      fwd_w1, fwd_w2, bwd_w1, bwd_w2, wt1, wt2);

  for (int l = 0; l < NLAYER; ++l) {
    const float *srcF, *srcB;
    int str;
    if (l == 0) {
      srcF = x; srcB = x; str = 512;
    } else {
      srcF = out + (size_t)(l - 1) * M_ROWS * 1024;
      srcB = srcF + 512;
      str = 1024;
    }
    const float* pLo = fwd_pad + (size_t)l * 3 * D_DIM;
    const float* pHi = bwd_pad + (size_t)l * 3 * D_DIM;

    conv_ln_kernel<<<dim3(M_ROWS / 4, 2), 256, 0, stream>>>(
        srcF, str, srcB, str, pLo, pHi,
        fwd_w + l * 4, bwd_w + l * 4,
        fwd_g + l * D_DIM, fwd_beta + l * D_DIM,
        bwd_g + l * D_DIM, bwd_beta + l * D_DIM,
        yln);

    gemm_kernel<1><<<1024, 256, 0, stream>>>(
        yln, wt1 + (size_t)l * WSZ, wt1 + (size_t)(NLAYER + l) * WSZ,
        fwd_b1 + l * D_DIM, bwd_b1 + l * D_DIM,
        h, nullptr,
        nullptr, nullptr, 0, nullptr, nullptr, nullptr, nullptr);

    gemm_kernel<2><<<1024, 256, 0, stream>>>(
        h, wt2 + (size_t)l * WSZ, wt2 + (size_t)(NLAYER + l) * WSZ,
        fwd_b2 + l * D_DIM, bwd_b2 + l * D_DIM,
        nullptr, out + (size_t)l * M_ROWS * 1024,
        srcF, srcB, str, pLo, pHi,
        fwd_w + l * 4, bwd_w + l * 4);
  }
}